// Round 14
// baseline (273.235 us; speedup 1.0000x reference)
//
#include <hip/hip_runtime.h>
#include <stdint.h>

typedef __bf16 bf16;
typedef float f32x4 __attribute__((ext_vector_type(4)));
typedef bf16 bf16x8 __attribute__((ext_vector_type(8)));
typedef bf16 bf16x4 __attribute__((ext_vector_type(4)));

#define MFMA16(a, b, c) __builtin_amdgcn_mfma_f32_16x16x32_bf16((a), (b), (c), 0, 0, 0)

static __device__ __forceinline__ void load_lds16(const bf16* g, bf16* l) {
  __builtin_amdgcn_global_load_lds(
      (const __attribute__((address_space(1))) void*)g,
      (__attribute__((address_space(3))) void*)l, 16, 0, 0);
}

// XCD-chunked block swizzle (T1). nwg%8==0 for all users (1152/768/768).
static __device__ __forceinline__ void xcd_swz(int& bx, int& by, int& bz) {
  int gx = gridDim.x, gy = gridDim.y;
  int lin = blockIdx.x + gx * (blockIdx.y + gy * blockIdx.z);
  int nwg = gx * gy * gridDim.z;
  int nl = (lin & 7) * (nwg >> 3) + (lin >> 3);
  bx = nl % gx;
  int t = nl / gx;
  by = t % gy;
  bz = t / gy;
}

// ---------------------------------------------------------------------------
// Fused prep: blocks [0,6912) transpose+convert the 6 weight matrices
// (fp32 [R][C] -> bf16 [C][R]); blocks [6912,11008) do LayerNorm1 rows.
// ---------------------------------------------------------------------------
__global__ void __launch_bounds__(256) k_prep(
    const float* __restrict__ x, const float* __restrict__ ln1g,
    const float* __restrict__ ln1b, bf16* __restrict__ h1,
    const float* s0, const float* s1, const float* s2, const float* s3,
    const float* s4, const float* s5,
    bf16* d0, bf16* d1, bf16* d2, bf16* d3, bf16* d4, bf16* d5) {
  int t = blockIdx.x;
  int tid = threadIdx.x;
  if (t < 6912) {
    const float* src; bf16* dst; int R, C;
    if (t < 2304) {
      int z = t / 576; t -= z * 576;
      src = (z == 0) ? s0 : (z == 1) ? s1 : (z == 2) ? s2 : s3;
      dst = (z == 0) ? d0 : (z == 1) ? d1 : (z == 2) ? d2 : d3;
      R = 768; C = 768;
    } else if (t < 4608) {
      t -= 2304; src = s4; dst = d4; R = 768; C = 3072;
    } else {
      t -= 4608; src = s5; dst = d5; R = 3072; C = 768;
    }
    int tcn = C >> 5;
    int tr = t / tcn, tc = t % tcn;
    __shared__ float tile[32][33];
    int tx = tid & 31, ty = tid >> 5;
    for (int i = 0; i < 4; i++)
      tile[ty + i * 8][tx] = src[(size_t)(tr * 32 + ty + i * 8) * C + tc * 32 + tx];
    __syncthreads();
    for (int i = 0; i < 4; i++)
      dst[(size_t)(tc * 32 + ty + i * 8) * R + tr * 32 + tx] = (bf16)tile[tx][ty + i * 8];
  } else {
    int row = t - 6912;
    const float* rp = x + (size_t)row * 768;
    float v0 = rp[tid], v1 = rp[tid + 256], v2 = rp[tid + 512];
    float s = v0 + v1 + v2, sq = v0 * v0 + v1 * v1 + v2 * v2;
    for (int off = 1; off < 64; off <<= 1) {
      s += __shfl_xor(s, off, 64);
      sq += __shfl_xor(sq, off, 64);
    }
    __shared__ float ps[8];
    if ((tid & 63) == 0) { ps[tid >> 6] = s; ps[4 + (tid >> 6)] = sq; }
    __syncthreads();
    s = ps[0] + ps[1] + ps[2] + ps[3];
    sq = ps[4] + ps[5] + ps[6] + ps[7];
    float mu = s * (1.0f / 768.0f);
    float rstd = rsqrtf(sq * (1.0f / 768.0f) - mu * mu + 1e-5f);
    bf16* op = h1 + (size_t)row * 768;
    op[tid] = (bf16)((v0 - mu) * rstd * ln1g[tid] + ln1b[tid]);
    op[tid + 256] = (bf16)((v1 - mu) * rstd * ln1g[tid + 256] + ln1b[tid + 256]);
    op[tid + 512] = (bf16)((v2 - mu) * rstd * ln1g[tid + 512] + ln1b[tid + 512]);
  }
}

// ---------------------------------------------------------------------------
// LN2 + WO-split-K reduce: x1 = p0 + p1 + x + bo; h2 = LN(x1). All streams
// coalesced fp32 (R12 lesson: folding into GEMM epilogues costs more).
// ---------------------------------------------------------------------------
__global__ void __launch_bounds__(256) k_ln2_reduce(
    const float* __restrict__ p0, const float* __restrict__ p1,
    const float* __restrict__ x, const float* __restrict__ bo,
    const float* __restrict__ gam, const float* __restrict__ bet,
    float* __restrict__ x1, bf16* __restrict__ h2) {
  int row = blockIdx.x, tid = threadIdx.x;
  size_t base = (size_t)row * 768;
  float v0 = p0[base + tid] + p1[base + tid] + x[base + tid] + bo[tid];
  float v1 = p0[base + tid + 256] + p1[base + tid + 256] + x[base + tid + 256] + bo[tid + 256];
  float v2 = p0[base + tid + 512] + p1[base + tid + 512] + x[base + tid + 512] + bo[tid + 512];
  x1[base + tid] = v0; x1[base + tid + 256] = v1; x1[base + tid + 512] = v2;
  float s = v0 + v1 + v2, sq = v0 * v0 + v1 * v1 + v2 * v2;
  for (int off = 1; off < 64; off <<= 1) {
    s += __shfl_xor(s, off, 64);
    sq += __shfl_xor(sq, off, 64);
  }
  __shared__ float ps[8];
  if ((tid & 63) == 0) { ps[tid >> 6] = s; ps[4 + (tid >> 6)] = sq; }
  __syncthreads();
  s = ps[0] + ps[1] + ps[2] + ps[3];
  sq = ps[4] + ps[5] + ps[6] + ps[7];
  float mu = s * (1.0f / 768.0f);
  float rstd = rsqrtf(sq * (1.0f / 768.0f) - mu * mu + 1e-5f);
  bf16* op = h2 + base;
  op[tid] = (bf16)((v0 - mu) * rstd * gam[tid] + bet[tid]);
  op[tid + 256] = (bf16)((v1 - mu) * rstd * gam[tid + 256] + bet[tid + 256]);
  op[tid + 512] = (bf16)((v2 - mu) * rstd * gam[tid + 512] + bet[tid + 512]);
}

// ---------------------------------------------------------------------------
// FF2 reduce (split-2): d_out = x1 + b2 + f0 + f1 (fp32, vectorized x4)
// ---------------------------------------------------------------------------
__global__ void __launch_bounds__(256) k_ff2_reduce(
    const float* __restrict__ f0, const float* __restrict__ f1,
    const float* __restrict__ x1, const float* __restrict__ b2,
    float* __restrict__ out) {
  size_t i = ((size_t)blockIdx.x * 256 + threadIdx.x) * 4;
  int col = (int)(i % 768);
  f32x4 v = *(const f32x4*)(x1 + i);
  f32x4 b = *(const f32x4*)(b2 + col);
  f32x4 a0 = *(const f32x4*)(f0 + i), a1 = *(const f32x4*)(f1 + i);
  *(f32x4*)(out + i) = v + b + a0 + a1;
}

// ---------------------------------------------------------------------------
// GEMM core BK=32 MT=4 depth-2 (FF1): 16 MFMA/barrier, 128x128 tile --
// lowest staging-bytes-per-FLOP config. 3 LDS buffers, counted vmcnt.
// ---------------------------------------------------------------------------
template <int MT>
static __device__ __forceinline__ void gemm_core(
    const bf16* __restrict__ A, int lda, const bf16* __restrict__ Bt, int ldb,
    int Kc, int m0, int n0, bf16* As, bf16* Bs, f32x4 acc[MT][4]) {
  int tid = threadIdx.x, w = tid >> 6, lane = tid & 63, quad = lane >> 4, l15 = lane & 15;
  int wr = w >> 1, wc = w & 1;
  int srow = lane >> 2;
  int sk = (((lane & 3) ^ ((srow >> 1) & 3)) * 8);
  int rsw = ((l15 >> 1) & 3);
  const int ABUF = MT * 32 * 32;
  const int BBUF = 128 * 32;

  auto stage = [&](int k0, int buf) {
    bf16* Ab = As + buf * ABUF;
    bf16* Bb = Bs + buf * BBUF;
    if (MT == 4) {
      for (int c = 0; c < 2; c++) {
        int seg = w * 2 + c;
        load_lds16(A + (size_t)(m0 + seg * 16 + srow) * lda + k0 + sk, Ab + seg * 512);
      }
    } else {
      load_lds16(A + (size_t)(m0 + w * 16 + srow) * lda + k0 + sk, Ab + w * 512);
    }
    for (int c = 0; c < 2; c++) {
      int seg = w * 2 + c;
      load_lds16(Bt + (size_t)(n0 + seg * 16 + srow) * ldb + k0 + sk, Bb + seg * 512);
    }
  };

  stage(0, 0);
  stage(32, 1);
  int cur = 0;
  for (int k0 = 0; k0 < Kc; k0 += 32) {
    if (k0 + 32 < Kc) {
      if (MT == 4) asm volatile("s_waitcnt vmcnt(4)" ::: "memory");
      else         asm volatile("s_waitcnt vmcnt(3)" ::: "memory");
    } else {
      asm volatile("s_waitcnt vmcnt(0)" ::: "memory");
    }
    __builtin_amdgcn_s_barrier();
    __builtin_amdgcn_sched_barrier(0);
    if (k0 + 64 < Kc) {
      int nb = cur + 2; if (nb >= 3) nb -= 3;
      stage(k0 + 64, nb);
    }
    const bf16* Ab = As + cur * ABUF;
    const bf16* Bb = Bs + cur * BBUF;
    bf16x8 af[MT], bfr[4];
    for (int mi = 0; mi < MT; mi++)
      af[mi] = *(const bf16x8*)(Ab + (wr * (MT * 16) + mi * 16 + l15) * 32 + ((quad ^ rsw) * 8));
    for (int ni = 0; ni < 4; ni++)
      bfr[ni] = *(const bf16x8*)(Bb + (wc * 64 + ni * 16 + l15) * 32 + ((quad ^ rsw) * 8));
    for (int mi = 0; mi < MT; mi++)
      for (int ni = 0; ni < 4; ni++)
        acc[mi][ni] = MFMA16(af[mi], bfr[ni], acc[mi][ni]);
    cur = cur + 1; if (cur >= 3) cur -= 3;
  }
}

// ---------------------------------------------------------------------------
// GEMM core BK=64 (MT=2): 16 MFMA + 12 ds_read per barrier. R9-proven for
// short-K GEMMs (QKV/WO/FF2: step-overhead-bound, not staging-bound).
// ---------------------------------------------------------------------------
static __device__ __forceinline__ void gemm_core64(
    const bf16* __restrict__ A, int lda, const bf16* __restrict__ Bt, int ldb,
    int Kc, int m0, int n0, bf16* As, bf16* Bs, f32x4 acc[2][4]) {
  int tid = threadIdx.x, w = tid >> 6, lane = tid & 63, quad = lane >> 4, l15 = lane & 15;
  int wr = w >> 1, wc = w & 1;
  int srow = lane >> 2;
  int sk = (((lane & 3) ^ ((srow >> 1) & 3)) * 8);
  int rsw = ((l15 >> 1) & 3);
  const int ASUB = 2 * 32 * 32;
  const int BSUB = 128 * 32;
  const int ABUF = 2 * ASUB;
  const int BBUF = 2 * BSUB;

  auto stage = [&](int k0, int buf) {
    bf16* Ab = As + buf * ABUF;
    bf16* Bb = Bs + buf * BBUF;
    for (int h = 0; h < 2; h++) {
      load_lds16(A + (size_t)(m0 + w * 16 + srow) * lda + k0 + h * 32 + sk,
                 Ab + h * ASUB + w * 512);
      for (int c = 0; c < 2; c++) {
        int seg = w * 2 + c;
        load_lds16(Bt + (size_t)(n0 + seg * 16 + srow) * ldb + k0 + h * 32 + sk,
                   Bb + h * BSUB + seg * 512);
      }
    }
  };

  stage(0, 0);
  int cur = 0;
  for (int k0 = 0; k0 < Kc; k0 += 64) {
    __syncthreads();  // buf[cur] staged (issued one full 64-K step ago)
    if (k0 + 64 < Kc) stage(k0 + 64, cur ^ 1);
    const bf16* Ab = As + cur * ABUF;
    const bf16* Bb = Bs + cur * BBUF;
    for (int h = 0; h < 2; h++) {
      bf16x8 af[2], bfr[4];
      for (int mi = 0; mi < 2; mi++)
        af[mi] = *(const bf16x8*)(Ab + h * ASUB +
                 (wr * 32 + mi * 16 + l15) * 32 + ((quad ^ rsw) * 8));
      for (int ni = 0; ni < 4; ni++)
        bfr[ni] = *(const bf16x8*)(Bb + h * BSUB +
                  (wc * 64 + ni * 16 + l15) * 32 + ((quad ^ rsw) * 8));
      for (int mi = 0; mi < 2; mi++)
        for (int ni = 0; ni < 4; ni++)
          acc[mi][ni] = MFMA16(af[mi], bfr[ni], acc[mi][ni]);
    }
    cur ^= 1;
  }
}

// Full-K GEMM (FF1), BK=32 MT=4 depth-2: relu -> bf16 out. Grid (24,32).
__global__ void __launch_bounds__(256, 3) k_gemm(
    const bf16* __restrict__ A, const bf16* __restrict__ Bt,
    const float* __restrict__ bias, bf16* __restrict__ outp, int K_, int N_) {
  __shared__ __align__(16) bf16 As[3 * 4 * 32 * 32];
  __shared__ __align__(16) bf16 Bs[3 * 128 * 32];
  int bx, by, bz;
  xcd_swz(bx, by, bz);
  int m0 = by * 128, n0 = bx * 128;
  f32x4 acc[4][4] = {};
  gemm_core<4>(A, K_, Bt, K_, K_, m0, n0, As, Bs, acc);
  int tid = threadIdx.x, w = tid >> 6, lane = tid & 63, quad = lane >> 4, l15 = lane & 15;
  int wr = w >> 1, wc = w & 1;
  float bv[4];
  for (int ni = 0; ni < 4; ni++) bv[ni] = bias[n0 + wc * 64 + ni * 16 + l15];
  for (int mi = 0; mi < 4; mi++) {
    int mb = m0 + wr * 64 + mi * 16 + quad * 4;
    for (int ni = 0; ni < 4; ni++) {
      int n = n0 + wc * 64 + ni * 16 + l15;
      for (int r = 0; r < 4; r++) {
        float val = acc[mi][ni][r] + bv[ni];
        outp[(size_t)(mb + r) * N_ + n] = (bf16)fmaxf(val, 0.0f);
      }
    }
  }
}

// Split-K GEMM (WO, FF2), BK=64 MT=2, split-2: raw fp32 partials.
__global__ void __launch_bounds__(256, 3) k_gemm_split64(
    const bf16* __restrict__ A, const bf16* __restrict__ Bt,
    float* __restrict__ f0, float* __restrict__ f1, int K_, int Kc, int N_) {
  __shared__ __align__(16) bf16 As[2 * 2 * 2 * 32 * 32];
  __shared__ __align__(16) bf16 Bs[2 * 2 * 128 * 32];
  int bx, by, bz;
  xcd_swz(bx, by, bz);
  float* outp = (bz == 0) ? f0 : f1;
  int m0 = by * 64, n0 = bx * 128;
  f32x4 acc[2][4] = {};
  gemm_core64(A + (size_t)bz * Kc, K_, Bt + (size_t)bz * Kc, K_, Kc, m0, n0, As, Bs, acc);
  int tid = threadIdx.x, w = tid >> 6, lane = tid & 63, quad = lane >> 4, l15 = lane & 15;
  int wr = w >> 1, wc = w & 1;
  for (int mi = 0; mi < 2; mi++) {
    int mb = m0 + wr * 32 + mi * 16 + quad * 4;
    for (int ni = 0; ni < 4; ni++) {
      int n = n0 + wc * 64 + ni * 16 + l15;
      for (int r = 0; r < 4; r++)
        outp[(size_t)(mb + r) * N_ + n] = acc[mi][ni][r];
    }
  }
}

// QKV projection, BK=64 MT=2: z selects weight; q/k [B,H,S,64], v [B,H,64,S].
// Q pre-scaled by (1/sqrt(64))*log2(e) so attn's softmax skips the multiply.
__global__ void __launch_bounds__(256, 3) k_gemm_qkv64(
    const bf16* __restrict__ h1, const bf16* __restrict__ wqT,
    const bf16* __restrict__ wkT, const bf16* __restrict__ wvT,
    const float* __restrict__ bq, const float* __restrict__ bk,
    const float* __restrict__ bv, bf16* __restrict__ qb,
    bf16* __restrict__ kb, bf16* __restrict__ vtb) {
  __shared__ __align__(16) bf16 As[2 * 2 * 2 * 32 * 32];
  __shared__ __align__(16) bf16 Bs[2 * 2 * 128 * 32];
  int bx, by, bz;
  xcd_swz(bx, by, bz);
  int z = bz;
  const bf16* Bt = (z == 0) ? wqT : (z == 1) ? wkT : wvT;
  const float* bias = (z == 0) ? bq : (z == 1) ? bk : bv;
  int m0 = by * 64, n0 = bx * 128;
  f32x4 acc[2][4] = {};
  gemm_core64(h1, 768, Bt, 768, 768, m0, n0, As, Bs, acc);
  int tid = threadIdx.x, w = tid >> 6, lane = tid & 63, quad = lane >> 4, l15 = lane & 15;
  int wr = w >> 1, wc = w & 1;
  const float C2 = 0.18033688011112042f;  // (1/sqrt(64)) * log2(e)
  float qs = (z == 0) ? C2 : 1.0f;
  float bvv[4];
  for (int ni = 0; ni < 4; ni++) bvv[ni] = bias[n0 + wc * 64 + ni * 16 + l15];
  for (int mi = 0; mi < 2; mi++) {
    int mb = m0 + wr * 32 + mi * 16 + quad * 4;  // token index (4-aligned)
    int b = mb >> 11, s0_ = mb & 2047;
    for (int ni = 0; ni < 4; ni++) {
      int n = n0 + wc * 64 + ni * 16 + l15;
      int h = n >> 6, hd = n & 63;
      if (z < 2) {
        bf16* outp = (z == 0) ? qb : kb;
        size_t base = (size_t)(b * 12 + h) * 2048 * 64;
        for (int r = 0; r < 4; r++)
          outp[base + (size_t)(s0_ + r) * 64 + hd] = (bf16)((acc[mi][ni][r] + bvv[ni]) * qs);
      } else {
        bf16x4 pk;
        for (int r = 0; r < 4; r++) pk[r] = (bf16)(acc[mi][ni][r] + bvv[ni]);
        *(bf16x4*)(vtb + (((size_t)(b * 12 + h) * 64 + hd) * 2048 + s0_)) = pk;
      }
    }
  }
}

// ---------------------------------------------------------------------------
// Flash attention v7: 48 KiB LDS -> 3 blocks/CU (12 waves, +50% TLP vs v6).
//   - K double-buffered; V SINGLE-buffered with counted-vmcnt cover: V loads
//     issued FIRST (oldest), K(t+1) after; pre-PV wait is vmcnt(4) so
//     K(t+1) stays in flight across the raw s_barrier (T4 -- no drain).
//   - Ps eliminated: P written into Ks[cur] after a lgkm-only raw barrier
//     (all QK reads of it are done; vmcnt untouched). Per-wave 4KB quarter.
//   - Entry barrier = __syncthreads (vmcnt(0) wanted: only K(t) outstanding,
//     which had a full tile of cover).
//   - All 768 blocks resident at 3/CU -> parity-interleaved qt map for
//     static per-CU balance (descending sort is for the refill regime).
// ---------------------------------------------------------------------------
__global__ void __launch_bounds__(256, 3) k_attn(
    const bf16* __restrict__ qb, const bf16* __restrict__ kb,
    const bf16* __restrict__ vtb, bf16* __restrict__ out) {
  __shared__ __align__(16) bf16 Ks[2 * 128 * 64];
  __shared__ __align__(16) bf16 Vs[64 * 128];
  int g = blockIdx.x / 24;
  int bh = blockIdx.x % 24;
  int qt = (g & 1) ? (g >> 1) : (31 - (g >> 1));
  int q0 = qt * 64;
  int tid = threadIdx.x, w = tid >> 6, lane = tid & 63, quad = lane >> 4, l15 = lane & 15;
  const bf16* qbase = qb + (size_t)bh * 2048 * 64;
  const bf16* kbase = kb + (size_t)bh * 2048 * 64;
  const bf16* vbase = vtb + (size_t)bh * 64 * 2048;

  bf16x8 qf[2];
  for (int ds = 0; ds < 2; ds++)
    qf[ds] = *(const bf16x8*)(qbase + (size_t)(q0 + w * 16 + l15) * 64 + ds * 32 + quad * 8);

  bf16 one_ = (bf16)1.0f;
  bf16x8 ones8 = {one_, one_, one_, one_, one_, one_, one_, one_};

  f32x4 o[4] = {};
  f32x4 lacc = {};

  auto stageK = [&](int k0, int buf) {
    int rsub = lane >> 3, c8 = lane & 7;
    bf16* Kb = Ks + buf * (128 * 64);
    for (int c = 0; c < 4; c++) {
      int seg = c * 4 + w;
      int row = seg * 8 + rsub;
      load_lds16(kbase + (size_t)(k0 + row) * 64 + ((c8 ^ (row & 7)) * 8), Kb + seg * 512);
    }
  };
  auto stageV = [&](int k0) {
    int rsub2 = lane >> 4, c16 = lane & 15;
    for (int c = 0; c < 4; c++) {
      int seg = c * 4 + w;
      int row = seg * 4 + rsub2;
      load_lds16(vbase + (size_t)row * 2048 + k0 + ((c16 ^ (row & 15)) * 8), Vs + seg * 512);
    }
  };

  int nkt = (qt >> 1) + 1;
  stageK(0, 0);
  int cur = 0;
  for (int kt = 0; kt < nkt; kt++) {
    int k0 = kt * 128;
    __syncthreads();  // vmcnt(0)+barrier: K(t) landed in Ks[cur]; PV(t-1) done
    stageV(k0);                          // V loads FIRST (oldest in queue)
    __builtin_amdgcn_sched_barrier(0);   // pin issue order: V before K
    if (kt + 1 < nkt) stageK(k0 + 128, cur ^ 1);
    const bf16* Kb = Ks + cur * (128 * 64);
    bf16* Pw = Ks + cur * (128 * 64) + w * 2048;  // P: own 4KB quarter of K buf

    // S = Q K^T : wave computes 16 q-rows x 128 k-cols (Q pre-scaled)
    f32x4 sc[8] = {};
    __builtin_amdgcn_s_setprio(1);
    for (int kj = 0; kj < 8; kj++) {
      int krow = kj * 16 + l15;
      for (int ds = 0; ds < 2; ds++) {
        bf16x8 kf = *(const bf16x8*)(Kb + krow * 64 + (((ds * 4 + quad) ^ (krow & 7)) * 8));
        sc[kj] = MFMA16(qf[ds], kf, sc[kj]);
      }
    }
    __builtin_amdgcn_s_setprio(0);
    if (kt == nkt - 1) {  // causal mask on the diagonal-overlapping tile
      int qg = q0 + w * 16 + quad * 4;
      for (int kj = 0; kj < 8; kj++) {
        int kg = k0 + kj * 16 + l15;
        for (int r = 0; r < 4; r++)
          if (kg > qg + r) sc[kj][r] = -3.0e38f;
      }
    }
    // softmax numerator (no max subtraction); row-sum comes from P@ones MFMA
    for (int kj = 0; kj < 8; kj++)
      for (int r = 0; r < 4; r++)
        sc[kj][r] = exp2f(sc[kj][r]);

    // barrier 2 (lgkm-only, raw): all waves' QK reads of Ks[cur] complete;
    // vmcnt untouched -> V(t)/K(t+1) prefetch stays in flight.
    asm volatile("s_waitcnt lgkmcnt(0)" ::: "memory");
    __builtin_amdgcn_s_barrier();
    __builtin_amdgcn_sched_barrier(0);

    // P: C-layout -> A-layout into own quarter of Ks[cur] (16-chunk XOR swz)
    for (int kj = 0; kj < 8; kj++) {
      int colb = kj * 16 + l15;
      int chb = colb >> 3, cin = colb & 7;
      for (int r = 0; r < 4; r++) {
        int prow = quad * 4 + r;
        Pw[prow * 128 + ((chb ^ prow) * 8) + cin] = (bf16)sc[kj][r];
      }
    }

    // barrier 3: V staged (counted vmcnt -- K(t+1)'s 4 loads stay in flight)
    if (kt + 1 < nkt) asm volatile("s_waitcnt vmcnt(4)" ::: "memory");
    else              asm volatile("s_waitcnt vmcnt(0)" ::: "memory");
    __builtin_amdgcn_s_barrier();
    __builtin_amdgcn_sched_barrier(0);

    // O += P V ; lacc += P 1  (own-region ds reads; in-wave lgkm dependency)
    __builtin_amdgcn_s_setprio(1);
    for (int ks = 0; ks < 4; ks++) {
      int prow = l15;
      bf16x8 pf = *(const bf16x8*)(Pw + prow * 128 + (((ks * 4 + quad) ^ prow) * 8));
      lacc = MFMA16(pf, ones8, lacc);
      for (int dj = 0; dj < 4; dj++) {
        int vrow = dj * 16 + l15;
        bf16x8 vf = *(const bf16x8*)(Vs + vrow * 128 + (((ks * 4 + quad) ^ (vrow & 15)) * 8));
        o[dj] = MFMA16(pf, vf, o[dj]);
      }
    }
    __builtin_amdgcn_s_setprio(0);
    cur ^= 1;
  }
  // epilogue: out[(b*2048+s)*768 + h*64 + d]
  int b = bh / 12, h = bh % 12;
  f32x4 rl;
  for (int r = 0; r < 4; r++) rl[r] = 1.0f / lacc[r];
  int srow = q0 + w * 16 + quad * 4;
  for (int dj = 0; dj < 4; dj++) {
    int d = h * 64 + dj * 16 + l15;
    for (int r = 0; r < 4; r++)
      out[(size_t)(b * 2048 + srow + r) * 768 + d] = (bf16)(o[dj][r] * rl[r]);
  }
}

// ---------------------------------------------------------------------------
extern "C" void kernel_launch(void* const* d_in, const int* in_sizes, int n_in,
                              void* d_out, int out_size, void* d_ws, size_t ws_size,
                              hipStream_t stream) {
  const float* x    = (const float*)d_in[0];
  const float* wq   = (const float*)d_in[1];
  const float* bq   = (const float*)d_in[2];
  const float* wk   = (const float*)d_in[3];
  const float* bk   = (const float*)d_in[4];
  const float* wv   = (const float*)d_in[5];
  const float* bv   = (const float*)d_in[6];
  const float* wo   = (const float*)d_in[7];
  const float* bo   = (const float*)d_in[8];
  const float* w1   = (const float*)d_in[9];
  const float* b1   = (const float*)d_in[10];
  const float* w2   = (const float*)d_in[11];
  const float* b2   = (const float*)d_in[12];
  const float* ln1g = (const float*)d_in[13];
  const float* ln1b = (const float*)d_in[14];
  const float* ln2g = (const float*)d_in[15];
  const float* ln2b = (const float*)d_in[16];

  char* p = (char*)d_ws;
  bf16* wqT = (bf16*)p; p += (size_t)768 * 768 * 2;
  bf16* wkT = (bf16*)p; p += (size_t)768 * 768 * 2;
  bf16* wvT = (bf16*)p; p += (size_t)768 * 768 * 2;
  bf16* woT = (bf16*)p; p += (size_t)768 * 768 * 2;
  bf16* w1T = (bf16*)p; p += (size_t)768 * 3072 * 2;
  bf16* w2T = (bf16*)p; p += (size_t)768 * 3072 * 2;
  bf16* h1   = (bf16*)p; p += (size_t)4096 * 768 * 2;   // dead after qkv
  bf16* qbuf = (bf16*)p; p += (size_t)4096 * 768 * 2;   // dead after attn
  bf16* kbuf = (bf16*)p; p += (size_t)4096 * 768 * 2;   // dead after attn
  bf16* vtb  = (bf16*)p; p += (size_t)4096 * 768 * 2;   // dead after attn
  bf16* att  = (bf16*)p; p += (size_t)4096 * 768 * 2;   // dead after WO
  float* x1  = (float*)p; p += (size_t)4096 * 768 * 4;
  bf16* h2   = (bf16*)p; p += (size_t)4096 * 768 * 2;
  bf16* ffm  = (bf16*)p; p += (size_t)4096 * 3072 * 2;
  float* p0  = (float*)p; p += (size_t)4096 * 768 * 4;  // WO partials; dead after LN2
  float* p1  = (float*)p; p += (size_t)4096 * 768 * 4;
  // FF2 fp32 partials (split-2) alias buffers dead by FF2 time:
  float* f0 = (float*)h1;    // h1+qbuf   (12.6 MB)
  float* f1 = (float*)kbuf;  // kbuf+vtb  (12.6 MB)

  k_prep<<<dim3(11008), dim3(256), 0, stream>>>(
      x, ln1g, ln1b, h1, wq, wk, wv, wo, w1, w2, wqT, wkT, wvT, woT, w1T, w2T);
  k_gemm_qkv64<<<dim3(6, 64, 3), dim3(256), 0, stream>>>(
      h1, wqT, wkT, wvT, bq, bk, bv, qbuf, kbuf, vtb);
  k_attn<<<dim3(768), dim3(256), 0, stream>>>(qbuf, kbuf, vtb, att);
  // WO split-2: pure-store partials
  k_gemm_split64<<<dim3(6, 64, 2), dim3(256), 0, stream>>>(
      att, woT, p0, p1, 768, 384, 768);
  k_ln2_reduce<<<dim3(4096), dim3(256), 0, stream>>>(
      p0, p1, x, bo, ln2g, ln2b, x1, h2);
  // FF1: MT=4/BK=32 depth-2 (lowest staging-bytes-per-FLOP)
  k_gemm<<<dim3(24, 32), dim3(256), 0, stream>>>(
      h2, w1T, b1, ffm, 768, 3072);
  k_gemm_split64<<<dim3(6, 64, 2), dim3(256), 0, stream>>>(
      ffm, w2T, f0, f1, 3072, 1536, 768);
  k_ff2_reduce<<<dim3(3072), dim3(256), 0, stream>>>(
      f0, f1, x1, b2, (float*)d_out);
}

// Round 15
// 265.183 us; speedup vs baseline: 1.0304x; 1.0304x over previous
//
#include <hip/hip_runtime.h>
#include <stdint.h>

typedef __bf16 bf16;
typedef float f32x4 __attribute__((ext_vector_type(4)));
typedef bf16 bf16x8 __attribute__((ext_vector_type(8)));
typedef bf16 bf16x4 __attribute__((ext_vector_type(4)));

#define MFMA16(a, b, c) __builtin_amdgcn_mfma_f32_16x16x32_bf16((a), (b), (c), 0, 0, 0)

static __device__ __forceinline__ void load_lds16(const bf16* g, bf16* l) {
  __builtin_amdgcn_global_load_lds(
      (const __attribute__((address_space(1))) void*)g,
      (__attribute__((address_space(3))) void*)l, 16, 0, 0);
}

// XCD-chunked block swizzle (T1). nwg%8==0 for all users (1152/768/768).
static __device__ __forceinline__ void xcd_swz(int& bx, int& by, int& bz) {
  int gx = gridDim.x, gy = gridDim.y;
  int lin = blockIdx.x + gx * (blockIdx.y + gy * blockIdx.z);
  int nwg = gx * gy * gridDim.z;
  int nl = (lin & 7) * (nwg >> 3) + (lin >> 3);
  bx = nl % gx;
  int t = nl / gx;
  by = t % gy;
  bz = t / gy;
}

// ---------------------------------------------------------------------------
// Fused prep: blocks [0,6912) transpose+convert the 6 weight matrices
// (fp32 [R][C] -> bf16 [C][R]); blocks [6912,11008) do LayerNorm1 rows.
// ---------------------------------------------------------------------------
__global__ void __launch_bounds__(256) k_prep(
    const float* __restrict__ x, const float* __restrict__ ln1g,
    const float* __restrict__ ln1b, bf16* __restrict__ h1,
    const float* s0, const float* s1, const float* s2, const float* s3,
    const float* s4, const float* s5,
    bf16* d0, bf16* d1, bf16* d2, bf16* d3, bf16* d4, bf16* d5) {
  int t = blockIdx.x;
  int tid = threadIdx.x;
  if (t < 6912) {
    const float* src; bf16* dst; int R, C;
    if (t < 2304) {
      int z = t / 576; t -= z * 576;
      src = (z == 0) ? s0 : (z == 1) ? s1 : (z == 2) ? s2 : s3;
      dst = (z == 0) ? d0 : (z == 1) ? d1 : (z == 2) ? d2 : d3;
      R = 768; C = 768;
    } else if (t < 4608) {
      t -= 2304; src = s4; dst = d4; R = 768; C = 3072;
    } else {
      t -= 4608; src = s5; dst = d5; R = 3072; C = 768;
    }
    int tcn = C >> 5;
    int tr = t / tcn, tc = t % tcn;
    __shared__ float tile[32][33];
    int tx = tid & 31, ty = tid >> 5;
    for (int i = 0; i < 4; i++)
      tile[ty + i * 8][tx] = src[(size_t)(tr * 32 + ty + i * 8) * C + tc * 32 + tx];
    __syncthreads();
    for (int i = 0; i < 4; i++)
      dst[(size_t)(tc * 32 + ty + i * 8) * R + tr * 32 + tx] = (bf16)tile[tx][ty + i * 8];
  } else {
    int row = t - 6912;
    const float* rp = x + (size_t)row * 768;
    float v0 = rp[tid], v1 = rp[tid + 256], v2 = rp[tid + 512];
    float s = v0 + v1 + v2, sq = v0 * v0 + v1 * v1 + v2 * v2;
    for (int off = 1; off < 64; off <<= 1) {
      s += __shfl_xor(s, off, 64);
      sq += __shfl_xor(sq, off, 64);
    }
    __shared__ float ps[8];
    if ((tid & 63) == 0) { ps[tid >> 6] = s; ps[4 + (tid >> 6)] = sq; }
    __syncthreads();
    s = ps[0] + ps[1] + ps[2] + ps[3];
    sq = ps[4] + ps[5] + ps[6] + ps[7];
    float mu = s * (1.0f / 768.0f);
    float rstd = rsqrtf(sq * (1.0f / 768.0f) - mu * mu + 1e-5f);
    bf16* op = h1 + (size_t)row * 768;
    op[tid] = (bf16)((v0 - mu) * rstd * ln1g[tid] + ln1b[tid]);
    op[tid + 256] = (bf16)((v1 - mu) * rstd * ln1g[tid + 256] + ln1b[tid + 256]);
    op[tid + 512] = (bf16)((v2 - mu) * rstd * ln1g[tid + 512] + ln1b[tid + 512]);
  }
}

// ---------------------------------------------------------------------------
// LN2 + WO-split-K reduce: x1 = p0 + p1 + x + bo; h2 = LN(x1). All streams
// coalesced fp32 (R12 lesson: folding into GEMM epilogues costs more).
// ---------------------------------------------------------------------------
__global__ void __launch_bounds__(256) k_ln2_reduce(
    const float* __restrict__ p0, const float* __restrict__ p1,
    const float* __restrict__ x, const float* __restrict__ bo,
    const float* __restrict__ gam, const float* __restrict__ bet,
    float* __restrict__ x1, bf16* __restrict__ h2) {
  int row = blockIdx.x, tid = threadIdx.x;
  size_t base = (size_t)row * 768;
  float v0 = p0[base + tid] + p1[base + tid] + x[base + tid] + bo[tid];
  float v1 = p0[base + tid + 256] + p1[base + tid + 256] + x[base + tid + 256] + bo[tid + 256];
  float v2 = p0[base + tid + 512] + p1[base + tid + 512] + x[base + tid + 512] + bo[tid + 512];
  x1[base + tid] = v0; x1[base + tid + 256] = v1; x1[base + tid + 512] = v2;
  float s = v0 + v1 + v2, sq = v0 * v0 + v1 * v1 + v2 * v2;
  for (int off = 1; off < 64; off <<= 1) {
    s += __shfl_xor(s, off, 64);
    sq += __shfl_xor(sq, off, 64);
  }
  __shared__ float ps[8];
  if ((tid & 63) == 0) { ps[tid >> 6] = s; ps[4 + (tid >> 6)] = sq; }
  __syncthreads();
  s = ps[0] + ps[1] + ps[2] + ps[3];
  sq = ps[4] + ps[5] + ps[6] + ps[7];
  float mu = s * (1.0f / 768.0f);
  float rstd = rsqrtf(sq * (1.0f / 768.0f) - mu * mu + 1e-5f);
  bf16* op = h2 + base;
  op[tid] = (bf16)((v0 - mu) * rstd * gam[tid] + bet[tid]);
  op[tid + 256] = (bf16)((v1 - mu) * rstd * gam[tid + 256] + bet[tid + 256]);
  op[tid + 512] = (bf16)((v2 - mu) * rstd * gam[tid + 512] + bet[tid + 512]);
}

// ---------------------------------------------------------------------------
// FF2 reduce (split-2): d_out = x1 + b2 + f0 + f1 (fp32, vectorized x4)
// ---------------------------------------------------------------------------
__global__ void __launch_bounds__(256) k_ff2_reduce(
    const float* __restrict__ f0, const float* __restrict__ f1,
    const float* __restrict__ x1, const float* __restrict__ b2,
    float* __restrict__ out) {
  size_t i = ((size_t)blockIdx.x * 256 + threadIdx.x) * 4;
  int col = (int)(i % 768);
  f32x4 v = *(const f32x4*)(x1 + i);
  f32x4 b = *(const f32x4*)(b2 + col);
  f32x4 a0 = *(const f32x4*)(f0 + i), a1 = *(const f32x4*)(f1 + i);
  *(f32x4*)(out + i) = v + b + a0 + a1;
}

// ---------------------------------------------------------------------------
// GEMM core BK=32 MT=4 depth-2 (FF1): 16 MFMA/barrier, 128x128 tile --
// lowest staging-bytes-per-FLOP config. 3 LDS buffers, counted vmcnt.
// ---------------------------------------------------------------------------
template <int MT>
static __device__ __forceinline__ void gemm_core(
    const bf16* __restrict__ A, int lda, const bf16* __restrict__ Bt, int ldb,
    int Kc, int m0, int n0, bf16* As, bf16* Bs, f32x4 acc[MT][4]) {
  int tid = threadIdx.x, w = tid >> 6, lane = tid & 63, quad = lane >> 4, l15 = lane & 15;
  int wr = w >> 1, wc = w & 1;
  int srow = lane >> 2;
  int sk = (((lane & 3) ^ ((srow >> 1) & 3)) * 8);
  int rsw = ((l15 >> 1) & 3);
  const int ABUF = MT * 32 * 32;
  const int BBUF = 128 * 32;

  auto stage = [&](int k0, int buf) {
    bf16* Ab = As + buf * ABUF;
    bf16* Bb = Bs + buf * BBUF;
    if (MT == 4) {
      for (int c = 0; c < 2; c++) {
        int seg = w * 2 + c;
        load_lds16(A + (size_t)(m0 + seg * 16 + srow) * lda + k0 + sk, Ab + seg * 512);
      }
    } else {
      load_lds16(A + (size_t)(m0 + w * 16 + srow) * lda + k0 + sk, Ab + w * 512);
    }
    for (int c = 0; c < 2; c++) {
      int seg = w * 2 + c;
      load_lds16(Bt + (size_t)(n0 + seg * 16 + srow) * ldb + k0 + sk, Bb + seg * 512);
    }
  };

  stage(0, 0);
  stage(32, 1);
  int cur = 0;
  for (int k0 = 0; k0 < Kc; k0 += 32) {
    if (k0 + 32 < Kc) {
      if (MT == 4) asm volatile("s_waitcnt vmcnt(4)" ::: "memory");
      else         asm volatile("s_waitcnt vmcnt(3)" ::: "memory");
    } else {
      asm volatile("s_waitcnt vmcnt(0)" ::: "memory");
    }
    __builtin_amdgcn_s_barrier();
    __builtin_amdgcn_sched_barrier(0);
    if (k0 + 64 < Kc) {
      int nb = cur + 2; if (nb >= 3) nb -= 3;
      stage(k0 + 64, nb);
    }
    const bf16* Ab = As + cur * ABUF;
    const bf16* Bb = Bs + cur * BBUF;
    bf16x8 af[MT], bfr[4];
    for (int mi = 0; mi < MT; mi++)
      af[mi] = *(const bf16x8*)(Ab + (wr * (MT * 16) + mi * 16 + l15) * 32 + ((quad ^ rsw) * 8));
    for (int ni = 0; ni < 4; ni++)
      bfr[ni] = *(const bf16x8*)(Bb + (wc * 64 + ni * 16 + l15) * 32 + ((quad ^ rsw) * 8));
    for (int mi = 0; mi < MT; mi++)
      for (int ni = 0; ni < 4; ni++)
        acc[mi][ni] = MFMA16(af[mi], bfr[ni], acc[mi][ni]);
    cur = cur + 1; if (cur >= 3) cur -= 3;
  }
}

// ---------------------------------------------------------------------------
// GEMM core BK=64 (MT=2): 16 MFMA + 12 ds_read per barrier. R9-proven for
// short-K GEMMs (QKV/WO/FF2: step-overhead-bound, not staging-bound).
// ---------------------------------------------------------------------------
static __device__ __forceinline__ void gemm_core64(
    const bf16* __restrict__ A, int lda, const bf16* __restrict__ Bt, int ldb,
    int Kc, int m0, int n0, bf16* As, bf16* Bs, f32x4 acc[2][4]) {
  int tid = threadIdx.x, w = tid >> 6, lane = tid & 63, quad = lane >> 4, l15 = lane & 15;
  int wr = w >> 1, wc = w & 1;
  int srow = lane >> 2;
  int sk = (((lane & 3) ^ ((srow >> 1) & 3)) * 8);
  int rsw = ((l15 >> 1) & 3);
  const int ASUB = 2 * 32 * 32;
  const int BSUB = 128 * 32;
  const int ABUF = 2 * ASUB;
  const int BBUF = 2 * BSUB;

  auto stage = [&](int k0, int buf) {
    bf16* Ab = As + buf * ABUF;
    bf16* Bb = Bs + buf * BBUF;
    for (int h = 0; h < 2; h++) {
      load_lds16(A + (size_t)(m0 + w * 16 + srow) * lda + k0 + h * 32 + sk,
                 Ab + h * ASUB + w * 512);
      for (int c = 0; c < 2; c++) {
        int seg = w * 2 + c;
        load_lds16(Bt + (size_t)(n0 + seg * 16 + srow) * ldb + k0 + h * 32 + sk,
                   Bb + h * BSUB + seg * 512);
      }
    }
  };

  stage(0, 0);
  int cur = 0;
  for (int k0 = 0; k0 < Kc; k0 += 64) {
    __syncthreads();  // buf[cur] staged (issued one full 64-K step ago)
    if (k0 + 64 < Kc) stage(k0 + 64, cur ^ 1);
    const bf16* Ab = As + cur * ABUF;
    const bf16* Bb = Bs + cur * BBUF;
    for (int h = 0; h < 2; h++) {
      bf16x8 af[2], bfr[4];
      for (int mi = 0; mi < 2; mi++)
        af[mi] = *(const bf16x8*)(Ab + h * ASUB +
                 (wr * 32 + mi * 16 + l15) * 32 + ((quad ^ rsw) * 8));
      for (int ni = 0; ni < 4; ni++)
        bfr[ni] = *(const bf16x8*)(Bb + h * BSUB +
                  (wc * 64 + ni * 16 + l15) * 32 + ((quad ^ rsw) * 8));
      for (int mi = 0; mi < 2; mi++)
        for (int ni = 0; ni < 4; ni++)
          acc[mi][ni] = MFMA16(af[mi], bfr[ni], acc[mi][ni]);
    }
    cur ^= 1;
  }
}

// Full-K GEMM (FF1), BK=32 MT=4 depth-2: relu -> bf16 out. Grid (24,32).
__global__ void __launch_bounds__(256, 3) k_gemm(
    const bf16* __restrict__ A, const bf16* __restrict__ Bt,
    const float* __restrict__ bias, bf16* __restrict__ outp, int K_, int N_) {
  __shared__ __align__(16) bf16 As[3 * 4 * 32 * 32];
  __shared__ __align__(16) bf16 Bs[3 * 128 * 32];
  int bx, by, bz;
  xcd_swz(bx, by, bz);
  int m0 = by * 128, n0 = bx * 128;
  f32x4 acc[4][4] = {};
  gemm_core<4>(A, K_, Bt, K_, K_, m0, n0, As, Bs, acc);
  int tid = threadIdx.x, w = tid >> 6, lane = tid & 63, quad = lane >> 4, l15 = lane & 15;
  int wr = w >> 1, wc = w & 1;
  float bv[4];
  for (int ni = 0; ni < 4; ni++) bv[ni] = bias[n0 + wc * 64 + ni * 16 + l15];
  for (int mi = 0; mi < 4; mi++) {
    int mb = m0 + wr * 64 + mi * 16 + quad * 4;
    for (int ni = 0; ni < 4; ni++) {
      int n = n0 + wc * 64 + ni * 16 + l15;
      for (int r = 0; r < 4; r++) {
        float val = acc[mi][ni][r] + bv[ni];
        outp[(size_t)(mb + r) * N_ + n] = (bf16)fmaxf(val, 0.0f);
      }
    }
  }
}

// Split-K GEMM (WO, FF2), BK=64 MT=2, split-2: raw fp32 partials.
__global__ void __launch_bounds__(256, 3) k_gemm_split64(
    const bf16* __restrict__ A, const bf16* __restrict__ Bt,
    float* __restrict__ f0, float* __restrict__ f1, int K_, int Kc, int N_) {
  __shared__ __align__(16) bf16 As[2 * 2 * 2 * 32 * 32];
  __shared__ __align__(16) bf16 Bs[2 * 2 * 128 * 32];
  int bx, by, bz;
  xcd_swz(bx, by, bz);
  float* outp = (bz == 0) ? f0 : f1;
  int m0 = by * 64, n0 = bx * 128;
  f32x4 acc[2][4] = {};
  gemm_core64(A + (size_t)bz * Kc, K_, Bt + (size_t)bz * Kc, K_, Kc, m0, n0, As, Bs, acc);
  int tid = threadIdx.x, w = tid >> 6, lane = tid & 63, quad = lane >> 4, l15 = lane & 15;
  int wr = w >> 1, wc = w & 1;
  for (int mi = 0; mi < 2; mi++) {
    int mb = m0 + wr * 32 + mi * 16 + quad * 4;
    for (int ni = 0; ni < 4; ni++) {
      int n = n0 + wc * 64 + ni * 16 + l15;
      for (int r = 0; r < 4; r++)
        outp[(size_t)(mb + r) * N_ + n] = acc[mi][ni][r];
    }
  }
}

// QKV projection, BK=64 MT=2: z selects weight; q/k [B,H,S,64], v [B,H,64,S].
// Q pre-scaled by (1/sqrt(64))*log2(e) so attn's softmax skips the multiply.
__global__ void __launch_bounds__(256, 3) k_gemm_qkv64(
    const bf16* __restrict__ h1, const bf16* __restrict__ wqT,
    const bf16* __restrict__ wkT, const bf16* __restrict__ wvT,
    const float* __restrict__ bq, const float* __restrict__ bk,
    const float* __restrict__ bv, bf16* __restrict__ qb,
    bf16* __restrict__ kb, bf16* __restrict__ vtb) {
  __shared__ __align__(16) bf16 As[2 * 2 * 2 * 32 * 32];
  __shared__ __align__(16) bf16 Bs[2 * 2 * 128 * 32];
  int bx, by, bz;
  xcd_swz(bx, by, bz);
  int z = bz;
  const bf16* Bt = (z == 0) ? wqT : (z == 1) ? wkT : wvT;
  const float* bias = (z == 0) ? bq : (z == 1) ? bk : bv;
  int m0 = by * 64, n0 = bx * 128;
  f32x4 acc[2][4] = {};
  gemm_core64(h1, 768, Bt, 768, 768, m0, n0, As, Bs, acc);
  int tid = threadIdx.x, w = tid >> 6, lane = tid & 63, quad = lane >> 4, l15 = lane & 15;
  int wr = w >> 1, wc = w & 1;
  const float C2 = 0.18033688011112042f;  // (1/sqrt(64)) * log2(e)
  float qs = (z == 0) ? C2 : 1.0f;
  float bvv[4];
  for (int ni = 0; ni < 4; ni++) bvv[ni] = bias[n0 + wc * 64 + ni * 16 + l15];
  for (int mi = 0; mi < 2; mi++) {
    int mb = m0 + wr * 32 + mi * 16 + quad * 4;  // token index (4-aligned)
    int b = mb >> 11, s0_ = mb & 2047;
    for (int ni = 0; ni < 4; ni++) {
      int n = n0 + wc * 64 + ni * 16 + l15;
      int h = n >> 6, hd = n & 63;
      if (z < 2) {
        bf16* outp = (z == 0) ? qb : kb;
        size_t base = (size_t)(b * 12 + h) * 2048 * 64;
        for (int r = 0; r < 4; r++)
          outp[base + (size_t)(s0_ + r) * 64 + hd] = (bf16)((acc[mi][ni][r] + bvv[ni]) * qs);
      } else {
        bf16x4 pk;
        for (int r = 0; r < 4; r++) pk[r] = (bf16)(acc[mi][ni][r] + bvv[ni]);
        *(bf16x4*)(vtb + (((size_t)(b * 12 + h) * 64 + hd) * 2048 + s0_)) = pk;
      }
    }
  }
}

// ---------------------------------------------------------------------------
// Flash attention v6 (best measured; v4/v7 LDS-shrink restructures both
// regressed -- one-barrier-per-tile with full double-buffering is the
// validated structure). Q pre-scaled at QKV; K AND V double-buffered
// (80 KiB, 2 blocks/CU); ONE barrier per KV tile; full-tile prefetch cover;
// descending qt sort; s_setprio around MFMA clusters; l_i = P @ ones MFMA.
// ---------------------------------------------------------------------------
__global__ void __launch_bounds__(256, 2) k_attn(
    const bf16* __restrict__ qb, const bf16* __restrict__ kb,
    const bf16* __restrict__ vtb, bf16* __restrict__ out) {
  __shared__ __align__(16) bf16 Ks[2 * 128 * 64];
  __shared__ __align__(16) bf16 Vs[2 * 64 * 128];
  __shared__ __align__(16) bf16 Ps[4][16 * 128];
  int qt = 31 - (blockIdx.x / 24);   // long blocks dispatched first
  int bh = blockIdx.x % 24;
  int q0 = qt * 64;
  int tid = threadIdx.x, w = tid >> 6, lane = tid & 63, quad = lane >> 4, l15 = lane & 15;
  const bf16* qbase = qb + (size_t)bh * 2048 * 64;
  const bf16* kbase = kb + (size_t)bh * 2048 * 64;
  const bf16* vbase = vtb + (size_t)bh * 64 * 2048;

  bf16x8 qf[2];
  for (int ds = 0; ds < 2; ds++)
    qf[ds] = *(const bf16x8*)(qbase + (size_t)(q0 + w * 16 + l15) * 64 + ds * 32 + quad * 8);

  bf16 one_ = (bf16)1.0f;
  bf16x8 ones8 = {one_, one_, one_, one_, one_, one_, one_, one_};

  f32x4 o[4] = {};
  f32x4 lacc = {};

  auto stageKV = [&](int k0, int buf) {
    int rsub = lane >> 3, c8 = lane & 7;
    bf16* Kb = Ks + buf * (128 * 64);
    for (int c = 0; c < 4; c++) {
      int seg = c * 4 + w;
      int row = seg * 8 + rsub;
      load_lds16(kbase + (size_t)(k0 + row) * 64 + ((c8 ^ (row & 7)) * 8), Kb + seg * 512);
    }
    int rsub2 = lane >> 4, c16 = lane & 15;
    bf16* Vb = Vs + buf * (64 * 128);
    for (int c = 0; c < 4; c++) {
      int seg = c * 4 + w;
      int row = seg * 4 + rsub2;
      load_lds16(vbase + (size_t)row * 2048 + k0 + ((c16 ^ (row & 15)) * 8), Vb + seg * 512);
    }
  };

  int nkt = (qt >> 1) + 1;
  stageKV(0, 0);
  int cur = 0;
  for (int kt = 0; kt < nkt; kt++) {
    int k0 = kt * 128;
    __syncthreads();  // buf[cur] staged; all prior reads of buf[cur^1] done
    if (kt + 1 < nkt) stageKV(k0 + 128, cur ^ 1);
    const bf16* Kb = Ks + cur * (128 * 64);
    const bf16* Vb = Vs + cur * (64 * 128);

    // S = Q K^T : wave computes 16 q-rows x 128 k-cols (Q pre-scaled)
    f32x4 sc[8] = {};
    __builtin_amdgcn_s_setprio(1);
    for (int kj = 0; kj < 8; kj++) {
      int krow = kj * 16 + l15;
      for (int ds = 0; ds < 2; ds++) {
        bf16x8 kf = *(const bf16x8*)(Kb + krow * 64 + (((ds * 4 + quad) ^ (krow & 7)) * 8));
        sc[kj] = MFMA16(qf[ds], kf, sc[kj]);
      }
    }
    __builtin_amdgcn_s_setprio(0);
    if (kt == nkt - 1) {  // causal mask on the diagonal-overlapping tile
      int qg = q0 + w * 16 + quad * 4;
      for (int kj = 0; kj < 8; kj++) {
        int kg = k0 + kj * 16 + l15;
        for (int r = 0; r < 4; r++)
          if (kg > qg + r) sc[kj][r] = -3.0e38f;
      }
    }
    // softmax numerator (no max subtraction); row-sum comes from P@ones MFMA
    for (int kj = 0; kj < 8; kj++)
      for (int r = 0; r < 4; r++)
        sc[kj][r] = exp2f(sc[kj][r]);
    // P: C-layout -> A-layout via per-wave LDS region (16-chunk XOR swizzle)
    for (int kj = 0; kj < 8; kj++) {
      int colb = kj * 16 + l15;
      int chb = colb >> 3, cin = colb & 7;
      for (int r = 0; r < 4; r++) {
        int prow = quad * 4 + r;
        Ps[w][prow * 128 + ((chb ^ prow) * 8) + cin] = (bf16)sc[kj][r];
      }
    }
    // O += P V ; lacc += P 1  (own-region ds reads; in-wave lgkm dependency)
    __builtin_amdgcn_s_setprio(1);
    for (int ks = 0; ks < 4; ks++) {
      int prow = l15;
      bf16x8 pf = *(const bf16x8*)(&Ps[w][prow * 128 + (((ks * 4 + quad) ^ prow) * 8)]);
      lacc = MFMA16(pf, ones8, lacc);
      for (int dj = 0; dj < 4; dj++) {
        int vrow = dj * 16 + l15;
        bf16x8 vf = *(const bf16x8*)(Vb + vrow * 128 + (((ks * 4 + quad) ^ (vrow & 15)) * 8));
        o[dj] = MFMA16(pf, vf, o[dj]);
      }
    }
    __builtin_amdgcn_s_setprio(0);
    cur ^= 1;
  }
  // epilogue: out[(b*2048+s)*768 + h*64 + d]
  int b = bh / 12, h = bh % 12;
  f32x4 rl;
  for (int r = 0; r < 4; r++) rl[r] = 1.0f / lacc[r];
  int srow = q0 + w * 16 + quad * 4;
  for (int dj = 0; dj < 4; dj++) {
    int d = h * 64 + dj * 16 + l15;
    for (int r = 0; r < 4; r++)
      out[(size_t)(b * 2048 + srow + r) * 768 + d] = (bf16)(o[dj][r] * rl[r]);
  }
}

// ---------------------------------------------------------------------------
extern "C" void kernel_launch(void* const* d_in, const int* in_sizes, int n_in,
                              void* d_out, int out_size, void* d_ws, size_t ws_size,
                              hipStream_t stream) {
  const float* x    = (const float*)d_in[0];
  const float* wq   = (const float*)d_in[1];
  const float* bq   = (const float*)d_in[2];
  const float* wk   = (const float*)d_in[3];
  const float* bk   = (const float*)d_in[4];
  const float* wv   = (const float*)d_in[5];
  const float* bv   = (const float*)d_in[6];
  const float* wo   = (const float*)d_in[7];
  const float* bo   = (const float*)d_in[8];
  const float* w1   = (const float*)d_in[9];
  const float* b1   = (const float*)d_in[10];
  const float* w2   = (const float*)d_in[11];
  const float* b2   = (const float*)d_in[12];
  const float* ln1g = (const float*)d_in[13];
  const float* ln1b = (const float*)d_in[14];
  const float* ln2g = (const float*)d_in[15];
  const float* ln2b = (const float*)d_in[16];

  char* p = (char*)d_ws;
  bf16* wqT = (bf16*)p; p += (size_t)768 * 768 * 2;
  bf16* wkT = (bf16*)p; p += (size_t)768 * 768 * 2;
  bf16* wvT = (bf16*)p; p += (size_t)768 * 768 * 2;
  bf16* woT = (bf16*)p; p += (size_t)768 * 768 * 2;
  bf16* w1T = (bf16*)p; p += (size_t)768 * 3072 * 2;
  bf16* w2T = (bf16*)p; p += (size_t)768 * 3072 * 2;
  bf16* h1   = (bf16*)p; p += (size_t)4096 * 768 * 2;   // dead after qkv
  bf16* qbuf = (bf16*)p; p += (size_t)4096 * 768 * 2;   // dead after attn
  bf16* kbuf = (bf16*)p; p += (size_t)4096 * 768 * 2;   // dead after attn
  bf16* vtb  = (bf16*)p; p += (size_t)4096 * 768 * 2;   // dead after attn
  bf16* att  = (bf16*)p; p += (size_t)4096 * 768 * 2;   // dead after WO
  float* x1  = (float*)p; p += (size_t)4096 * 768 * 4;
  bf16* h2   = (bf16*)p; p += (size_t)4096 * 768 * 2;
  bf16* ffm  = (bf16*)p; p += (size_t)4096 * 3072 * 2;
  float* p0  = (float*)p; p += (size_t)4096 * 768 * 4;  // WO partials; dead after LN2
  float* p1  = (float*)p; p += (size_t)4096 * 768 * 4;
  // FF2 fp32 partials (split-2) alias buffers dead by FF2 time:
  float* f0 = (float*)h1;    // h1+qbuf   (12.6 MB)
  float* f1 = (float*)kbuf;  // kbuf+vtb  (12.6 MB)

  k_prep<<<dim3(11008), dim3(256), 0, stream>>>(
      x, ln1g, ln1b, h1, wq, wk, wv, wo, w1, w2, wqT, wkT, wvT, woT, w1T, w2T);
  k_gemm_qkv64<<<dim3(6, 64, 3), dim3(256), 0, stream>>>(
      h1, wqT, wkT, wvT, bq, bk, bv, qbuf, kbuf, vtb);
  k_attn<<<dim3(768), dim3(256), 0, stream>>>(qbuf, kbuf, vtb, att);
  // WO split-2: pure-store partials
  k_gemm_split64<<<dim3(6, 64, 2), dim3(256), 0, stream>>>(
      att, woT, p0, p1, 768, 384, 768);
  k_ln2_reduce<<<dim3(4096), dim3(256), 0, stream>>>(
      p0, p1, x, bo, ln2g, ln2b, x1, h2);
  // FF1: MT=4/BK=32 depth-2 (lowest staging-bytes-per-FLOP)
  k_gemm<<<dim3(24, 32), dim3(256), 0, stream>>>(
      h2, w1T, b1, ffm, 768, 3072);
  k_gemm_split64<<<dim3(6, 64, 2), dim3(256), 0, stream>>>(
      ffm, w2T, f0, f1, 3072, 1536, 768);
  k_ff2_reduce<<<dim3(3072), dim3(256), 0, stream>>>(
      f0, f1, x1, b2, (float*)d_out);
}